// Round 2
// baseline (306.073 us; speedup 1.0000x reference)
//
#include <hip/hip_runtime.h>

// GraphNN collapsed to exact affine form:
//   Every layer is h_{l+1} = (h_l / n_l) @ W + b with n_l a GLOBAL scalar
//   => out = (x @ Mo + co) / n_out, Mo:64x64, with all n_l computable from
//   G = x^T x (64x64) and s = colsum(x) via n^2 = tr(M^T G M) + 2c.(sM) + B|c|^2.
// Pipeline: kG (bf16 MFMA Gram, partials in d_out) -> kGred -> 4x kLayer
// (fp32 exact chain: trace->inv_n, compose M, propagate c) -> kNorm -> kApply
// (bf16 MFMA x@Mo + co, scaled). Workspace use < 250 KB.

#define BATCH 262144
#define BF 262144.0f

// ws float offsets
#define OFF_G   0
#define OFF_S   4096
#define OFF_M2  8192
#define OFF_M3  24576
#define OFF_M4  40960
#define OFF_MO  57344
#define OFF_C2  61440
#define OFF_C3  61696
#define OFF_C4  61952
#define OFF_CO  62208
#define OFF_INV 62272

typedef __attribute__((ext_vector_type(8))) short bf16x8;   // 8 bf16 = 4 VGPRs
typedef __attribute__((ext_vector_type(4))) float f32x4;

__device__ __forceinline__ unsigned short f2bf(float f) {
  unsigned u = __builtin_bit_cast(unsigned, f);
  u += 0x7FFF + ((u >> 16) & 1);          // round-to-nearest-even
  return (unsigned short)(u >> 16);
}

__device__ __forceinline__ bf16x8 cvt8(f32x4 a, f32x4 b, float s) {
  bf16x8 t;
#pragma unroll
  for (int j = 0; j < 4; j++) {
    t[j]     = (short)f2bf(a[j] * s);
    t[j + 4] = (short)f2bf(b[j] * s);
  }
  return t;
}

// ---------- kG: per-block partial G = x^T x (bf16 MFMA) and partial s -------
// Gpart layout: [block][4160] = 4096 G + 64 s. Stored in d_out (scratch).
__global__ __launch_bounds__(256) void kG(const float* __restrict__ x,
                                          float* __restrict__ Gpart) {
  __shared__ bf16x8 xt[4][4][16];     // [ct][q][i] -> 8 consecutive rows (j)
  __shared__ float red[256];
  const int tid = threadIdx.x;
  const int lane = tid & 63, mt = tid >> 6;
  const int col = lane & 15, q = lane >> 4;

  f32x4 acc[4];
#pragma unroll
  for (int nt = 0; nt < 4; nt++) acc[nt] = (f32x4){0.f, 0.f, 0.f, 0.f};
  float sacc = 0.f;

  const int base = blockIdx.x * 65536;   // 1024 rows * 64 cols per block
  for (int c = 0; c < 32; c++) {
#pragma unroll
    for (int m = 0; m < 8; m++) {
      const int idx = m * 256 + tid;           // 0..2047 covering 32x64
      const float v = x[base + c * 2048 + idx];
      sacc += v;                               // column idx&63 == tid&63 fixed
      const int row = idx >> 6, cf = idx & 63;
      ((unsigned short*)&xt[cf >> 4][row >> 3][cf & 15])[row & 7] = f2bf(v);
    }
    __syncthreads();
    bf16x8 fr[4];
#pragma unroll
    for (int nt = 0; nt < 4; nt++) fr[nt] = xt[nt][q][col];
    const bf16x8 af = xt[mt][q][col];
#pragma unroll
    for (int nt = 0; nt < 4; nt++)
      acc[nt] = __builtin_amdgcn_mfma_f32_16x16x32_bf16(af, fr[nt], acc[nt], 0, 0, 0);
    __syncthreads();
  }

  float* myp = Gpart + (long)blockIdx.x * 4160;
#pragma unroll
  for (int nt = 0; nt < 4; nt++)
#pragma unroll
    for (int r = 0; r < 4; r++)
      myp[(mt * 16 + q * 4 + r) * 64 + nt * 16 + col] = acc[nt][r];

  red[tid] = sacc;
  __syncthreads();
  if (tid < 64) myp[4096 + tid] = red[tid] + red[tid + 64] + red[tid + 128] + red[tid + 192];
}

// ---------- kGred: reduce 256 partials -> G, s --------------------------------
__global__ __launch_bounds__(64) void kGred(const float* __restrict__ Gpart,
                                            float* __restrict__ G,
                                            float* __restrict__ s) {
  const int e = blockIdx.x * 64 + threadIdx.x;
  if (e >= 4160) return;
  float acc = 0.f;
  for (int b = 0; b < 256; b++) acc += Gpart[(long)b * 4160 + e];
  if (e < 4096) G[e] = acc;
  else          s[e - 4096] = acc;
}

// ---------- kLayer: one structural layer of the exact fp32 affine chain ------
// Block (p,k): computes inv_n_p from (Tin_p, cin_p, G, s), then
//   Tout_k[vo][w] += inv * sum_u Wm[p,k,vo,u] * Tin_p[u][w]     (atomic)
//   cout_k[vo]    += inv * sum_u cin_p[u] * Wm[p,k,vo,u] + bm[p,k,vo]
// Tin layout [p][v][w] (= M transposed), p-stride 4096. KN=4 mid, KN=1 out.
__global__ __launch_bounds__(256) void kLayer(const float* __restrict__ Tin,
                                              const float* __restrict__ cin,
                                              const float* __restrict__ Wm,
                                              const float* __restrict__ bm,
                                              const float* __restrict__ G,
                                              const float* __restrict__ s,
                                              float* __restrict__ Tout,
                                              float* __restrict__ cout,
                                              const int KN) {
  __shared__ float Tl[64][66], Gl[64][66], Wl[64][66];
  __shared__ float red[256];
  __shared__ float cl[64], sl[64];
  const int tid = threadIdx.x;
  const int p = blockIdx.x / KN, kk = blockIdx.x % KN;

#pragma unroll
  for (int m = 0; m < 16; m++) {
    const int li = m * 256 + tid;
    Tl[li >> 6][li & 63] = Tin[(long)p * 4096 + li];
    Gl[li >> 6][li & 63] = G[li];
    Wl[li >> 6][li & 63] = Wm[(long)(p * KN + kk) * 4096 + li];
  }
  if (tid < 64) { cl[tid] = cin[p * 64 + tid]; sl[tid] = s[tid]; }
  __syncthreads();

  // ---- n^2 = tr(T G T^T-ish) + 2 c.(s@M) + B |c|^2 (columns of M are Tl rows)
  {
    const int v = tid >> 2, iq = tid & 3;
    float part = 0.f;
    for (int i = 0; i < 16; i++) {
      const int ii = iq * 16 + i;
      float gv = 0.f;
#pragma unroll 8
      for (int u = 0; u < 64; u++) gv += Gl[ii][u] * Tl[v][u];
      part += Tl[v][ii] * gv;
    }
    if (iq == 0) {
      float sd = 0.f;
#pragma unroll 8
      for (int u = 0; u < 64; u++) sd += sl[u] * Tl[v][u];
      part += cl[v] * (2.f * sd + BF * cl[v]);
    }
    red[tid] = part;
  }
  __syncthreads();
  for (int st = 128; st > 0; st >>= 1) {
    if (tid < st) red[tid] += red[tid + st];
    __syncthreads();
  }
  const float inv = 1.0f / sqrtf(red[0]);

  // ---- compose: Tout_k[vo][w] += inv * sum_u Wl[vo][u] * Tl[u][w]
  {
    const int vo = tid >> 2, wr = (tid & 3) * 16;
    float accp[16];
#pragma unroll
    for (int ww = 0; ww < 16; ww++) accp[ww] = 0.f;
    for (int u = 0; u < 64; u++) {
      const float w0 = Wl[vo][u];
#pragma unroll
      for (int ww = 0; ww < 16; ww++) accp[ww] += w0 * Tl[u][wr + ww];
    }
#pragma unroll
    for (int ww = 0; ww < 16; ww++)
      atomicAdd(&Tout[(long)kk * 4096 + vo * 64 + wr + ww], inv * accp[ww]);
  }

  // ---- bias chain: cout_k[vo] += inv * (cin_p @ Wm_pk^T)[vo] + bm[p,k,vo]
  if (tid < 64) {
    float pc = 0.f;
#pragma unroll 8
    for (int u = 0; u < 64; u++) pc += cl[u] * Wl[tid][u];
    atomicAdd(&cout[kk * 64 + tid], inv * pc + bm[(long)(p * KN + kk) * 64 + tid]);
  }
}

// ---------- kNorm: final n_out from (MoT, co, G, s) -> inv ------------------
__global__ __launch_bounds__(256) void kNorm(const float* __restrict__ MoT,
                                             const float* __restrict__ co,
                                             const float* __restrict__ G,
                                             const float* __restrict__ s,
                                             float* __restrict__ invp) {
  __shared__ float Tl[64][66], Gl[64][66];
  __shared__ float red[256];
  __shared__ float cl[64], sl[64];
  const int tid = threadIdx.x;
#pragma unroll
  for (int m = 0; m < 16; m++) {
    const int li = m * 256 + tid;
    Tl[li >> 6][li & 63] = MoT[li];
    Gl[li >> 6][li & 63] = G[li];
  }
  if (tid < 64) { cl[tid] = co[tid]; sl[tid] = s[tid]; }
  __syncthreads();

  const int v = tid >> 2, iq = tid & 3;
  float part = 0.f;
  for (int i = 0; i < 16; i++) {
    const int ii = iq * 16 + i;
    float gv = 0.f;
#pragma unroll 8
    for (int u = 0; u < 64; u++) gv += Gl[ii][u] * Tl[v][u];
    part += Tl[v][ii] * gv;
  }
  if (iq == 0) {
    float sd = 0.f;
#pragma unroll 8
    for (int u = 0; u < 64; u++) sd += sl[u] * Tl[v][u];
    part += cl[v] * (2.f * sd + BF * cl[v]);
  }
  red[tid] = part;
  __syncthreads();
  for (int st = 128; st > 0; st >>= 1) {
    if (tid < st) red[tid] += red[tid + st];
    __syncthreads();
  }
  if (tid == 0) invp[0] = 1.0f / sqrtf(red[0]);
}

// ---------- kApply: out[b][v] = (x[b]@Mo[:,v] + co[v]) * inv ----------------
__global__ __launch_bounds__(256) void kApply(const float* __restrict__ x,
                                              const float* __restrict__ MoT,
                                              const float* __restrict__ co,
                                              const float* __restrict__ invp,
                                              float* __restrict__ out) {
  const int tid = threadIdx.x, lane = tid & 63, vt = tid >> 6;
  const int col = lane & 15, q = lane >> 4;
  const float inv = invp[0];

  bf16x8 bfr[2];
  const float* mr = MoT + (vt * 16 + col) * 64 + q * 8;
  bfr[0] = cvt8(*(const f32x4*)mr, *(const f32x4*)(mr + 4), inv);
  bfr[1] = cvt8(*(const f32x4*)(mr + 32), *(const f32x4*)(mr + 36), inv);
  const float cf = co[vt * 16 + col] * inv;

  for (int t = 0; t < 16; t++) {
    const int b0 = (blockIdx.x * 16 + t) * 16;
    const float* xr = x + (b0 + col) * 64 + q * 8;
    const bf16x8 a0 = cvt8(*(const f32x4*)xr, *(const f32x4*)(xr + 4), 1.f);
    const bf16x8 a1 = cvt8(*(const f32x4*)(xr + 32), *(const f32x4*)(xr + 36), 1.f);
    f32x4 acc = (f32x4){0.f, 0.f, 0.f, 0.f};
    acc = __builtin_amdgcn_mfma_f32_16x16x32_bf16(a0, bfr[0], acc, 0, 0, 0);
    acc = __builtin_amdgcn_mfma_f32_16x16x32_bf16(a1, bfr[1], acc, 0, 0, 0);
#pragma unroll
    for (int r = 0; r < 4; r++)
      out[(b0 + q * 4 + r) * 64 + vt * 16 + col] = acc[r] + cf;
  }
}

extern "C" void kernel_launch(void* const* d_in, const int* in_sizes, int n_in,
                              void* d_out, int out_size, void* d_ws, size_t ws_size,
                              hipStream_t stream) {
  const float* x    = (const float*)d_in[0];
  const float* Win  = (const float*)d_in[1];
  const float* bin  = (const float*)d_in[2];
  const float* Wmid = (const float*)d_in[3];
  const float* bmid = (const float*)d_in[4];
  const float* Wout = (const float*)d_in[5];
  const float* bout = (const float*)d_in[6];
  float* out = (float*)d_out;
  float* ws  = (float*)d_ws;
  float* Gpart = out;   // 4.26 MB scratch inside d_out; overwritten by kApply

  // zero the accumulated chain region (G..inv); re-poisoned to 0xAA each call
  hipMemsetAsync(d_ws, 0, (OFF_INV + 1) * sizeof(float), stream);

  kG   <<<256, 256, 0, stream>>>(x, Gpart);
  kGred<<<65, 64, 0, stream>>>(Gpart, ws + OFF_G, ws + OFF_S);
  kLayer<<<16, 256, 0, stream>>>(Win,          bin,          Wmid,          bmid,
                                 ws + OFF_G, ws + OFF_S, ws + OFF_M2, ws + OFF_C2, 4);
  kLayer<<<16, 256, 0, stream>>>(ws + OFF_M2, ws + OFF_C2, Wmid + 65536,  bmid + 1024,
                                 ws + OFF_G, ws + OFF_S, ws + OFF_M3, ws + OFF_C3, 4);
  kLayer<<<16, 256, 0, stream>>>(ws + OFF_M3, ws + OFF_C3, Wmid + 131072, bmid + 2048,
                                 ws + OFF_G, ws + OFF_S, ws + OFF_M4, ws + OFF_C4, 4);
  kLayer<<<4, 256, 0, stream>>>(ws + OFF_M4, ws + OFF_C4, Wout,          bout,
                                 ws + OFF_G, ws + OFF_S, ws + OFF_MO, ws + OFF_CO, 1);
  kNorm<<<1, 256, 0, stream>>>(ws + OFF_MO, ws + OFF_CO, ws + OFF_G, ws + OFF_S, ws + OFF_INV);
  kApply<<<1024, 256, 0, stream>>>(x, ws + OFF_MO, ws + OFF_CO, ws + OFF_INV, out);
}

// Round 3
// 271.585 us; speedup vs baseline: 1.1270x; 1.1270x over previous
//
#include <hip/hip_runtime.h>

// GraphNN collapsed to exact affine form:
//   out = (x @ Mo + co) / n_out, all layer norms from G = x^T x and s = colsum(x):
//   n^2 = sum_v T[v].G.T[v] + sum_v c[v]*(2 s.T[v] + B c[v]).
// Round 3: coalesced kGred, pipelined kG (f32x4 + reg prefetch), kLayer with
// partial-slot writes (no atomics, no memset), vectorized LDS (pad 68).

#define BATCH 262144
#define BF 262144.0f

// ws float offsets
#define OFF_G   0
#define OFF_S   4096
#define OFF_P0  8192
#define OFF_P1  131072
#define OFF_C0  262144
#define OFF_C1  263168
#define OFF_MO  264192
#define OFF_CO  268288

typedef __attribute__((ext_vector_type(8))) short bf16x8;   // 8 bf16 = 4 VGPRs
typedef __attribute__((ext_vector_type(4))) float f32x4;

__device__ __forceinline__ unsigned short f2bf(float f) {
  unsigned u = __builtin_bit_cast(unsigned, f);
  u += 0x7FFF + ((u >> 16) & 1);          // round-to-nearest-even
  return (unsigned short)(u >> 16);
}

__device__ __forceinline__ bf16x8 cvt8(f32x4 a, f32x4 b, float s) {
  bf16x8 t;
#pragma unroll
  for (int j = 0; j < 4; j++) {
    t[j]     = (short)f2bf(a[j] * s);
    t[j + 4] = (short)f2bf(b[j] * s);
  }
  return t;
}

// ---------- kG: per-block partial G = x^T x (bf16 MFMA) + partial colsum ----
// 256 blocks x 256 thr; block handles 1024 rows; reg-prefetch pipeline.
__global__ __launch_bounds__(256) void kG(const float* __restrict__ x,
                                          float* __restrict__ Gpart) {
  __shared__ __align__(16) unsigned short xts[4][4][16][8]; // [ct][rq][i][j]=x[rq*8+j][ct*16+i]
  __shared__ float sred[256][4];
  const int tid = threadIdx.x;
  const int lane = tid & 63, mt = tid >> 6;
  const int col = lane & 15, q = lane >> 4;
  const int row0 = tid >> 4;            // 0..15
  const int cf0  = (tid & 15) * 4;

  f32x4 acc[4];
#pragma unroll
  for (int nt = 0; nt < 4; nt++) acc[nt] = (f32x4){0.f, 0.f, 0.f, 0.f};
  float s0 = 0.f, s1 = 0.f, s2 = 0.f, s3 = 0.f;

  const float* bx = x + (long)blockIdx.x * 65536;
  f32x4 r0 = *(const f32x4*)(bx + tid * 4);
  f32x4 r1 = *(const f32x4*)(bx + 1024 + tid * 4);

  for (int c = 0; c < 32; c++) {
    __syncthreads();                    // prev MFMA done reading LDS
    s0 += r0[0] + r1[0]; s1 += r0[1] + r1[1];
    s2 += r0[2] + r1[2]; s3 += r0[3] + r1[3];
#pragma unroll
    for (int j = 0; j < 4; j++) {
      const int cf = cf0 + j;
      xts[cf >> 4][row0 >> 3][cf & 15][row0 & 7]        = f2bf(r0[j]);
      xts[cf >> 4][2 + (row0 >> 3)][cf & 15][row0 & 7]  = f2bf(r1[j]);
    }
    f32x4 r0n = r0, r1n = r1;
    if (c < 31) {
      r0n = *(const f32x4*)(bx + (c + 1) * 2048 + tid * 4);
      r1n = *(const f32x4*)(bx + (c + 1) * 2048 + 1024 + tid * 4);
    }
    __syncthreads();                    // tile ready
    const bf16x8 af = *(const bf16x8*)xts[mt][q][col];
#pragma unroll
    for (int nt = 0; nt < 4; nt++) {
      const bf16x8 bfr = *(const bf16x8*)xts[nt][q][col];
      acc[nt] = __builtin_amdgcn_mfma_f32_16x16x32_bf16(af, bfr, acc[nt], 0, 0, 0);
    }
    r0 = r0n; r1 = r1n;
  }

  float* myp = Gpart + (long)blockIdx.x * 4160;
#pragma unroll
  for (int nt = 0; nt < 4; nt++)
#pragma unroll
    for (int r = 0; r < 4; r++)
      myp[(mt * 16 + q * 4 + r) * 64 + nt * 16 + col] = acc[nt][r];

  sred[tid][0] = s0; sred[tid][1] = s1; sred[tid][2] = s2; sred[tid][3] = s3;
  __syncthreads();
  if (tid < 64) {
    float t = 0.f;
#pragma unroll
    for (int k2 = 0; k2 < 16; k2++) t += sred[(tid >> 2) + 16 * k2][tid & 3];
    myp[4096 + tid] = t;
  }
}

// ---------- kGred: reduce 256 partials -> G, s (coalesced) ------------------
__global__ __launch_bounds__(256) void kGred(const float* __restrict__ Gpart,
                                             float* __restrict__ G,
                                             float* __restrict__ s) {
  __shared__ float red[4][64];
  const int tid = threadIdx.x;
  const int e = blockIdx.x * 64 + (tid & 63);
  const int quarter = tid >> 6;
  float acc = 0.f;
#pragma unroll 4
  for (int j = 0; j < 64; j++)
    acc += Gpart[(long)(quarter * 64 + j) * 4160 + e];
  red[quarter][tid & 63] = acc;
  __syncthreads();
  if (tid < 64) {
    const float t = red[0][tid] + red[1][tid] + red[2][tid] + red[3][tid];
    const int ee = blockIdx.x * 64 + tid;
    if (ee < 4096) G[ee] = t;
    else           s[ee - 4096] = t;
  }
}

// ---------- kLayer: one structural layer of the exact fp32 affine chain -----
// Block (p,k): Tl = (first ? Win[p] : sum_p' Pprev[p'][p]); computes inv_p;
// writes Pout[p][k] = inv * W_pk @ Tl  and  cpart[p][k] (no atomics).
__global__ __launch_bounds__(256) void kLayer(const float* __restrict__ Tsrc,
                                              const float* __restrict__ csrc,
                                              const float* __restrict__ Wm,
                                              const float* __restrict__ bm,
                                              const float* __restrict__ G,
                                              const float* __restrict__ s,
                                              float* __restrict__ Pout,
                                              float* __restrict__ cpout,
                                              const int KN, const int first) {
  __shared__ float Tl[64][68], Gl[64][68], Wl[64][68];
  __shared__ float red[256];
  __shared__ __align__(16) float cl[64], sl[64];
  const int tid = threadIdx.x;
  const int p = blockIdx.x / KN, kk = blockIdx.x % KN;

#pragma unroll
  for (int m = 0; m < 16; m++) {
    const int li = m * 256 + tid;
    const int r = li >> 6, cc = li & 63;
    float tv;
    if (first) tv = Tsrc[p * 4096 + li];
    else tv = Tsrc[p * 4096 + li] + Tsrc[(4 + p) * 4096 + li] +
              Tsrc[(8 + p) * 4096 + li] + Tsrc[(12 + p) * 4096 + li];
    Tl[r][cc] = tv;
    Gl[r][cc] = G[li];
    Wl[r][cc] = Wm[(long)(p * KN + kk) * 4096 + li];
  }
  if (tid < 64) {
    float cv;
    if (first) cv = csrc[p * 64 + tid];
    else cv = csrc[p * 64 + tid] + csrc[(4 + p) * 64 + tid] +
              csrc[(8 + p) * 64 + tid] + csrc[(12 + p) * 64 + tid];
    cl[tid] = cv;
    sl[tid] = s[tid];
  }
  __syncthreads();

  // ---- n^2 quadratic form; thread (v=tid>>2, iq=tid&3), T-row in registers
  const int v = tid >> 2, iq = tid & 3;
  f32x4 Tr[16];
#pragma unroll
  for (int u4 = 0; u4 < 16; u4++) Tr[u4] = *(const f32x4*)&Tl[v][u4 * 4];
  float part = 0.f;
  for (int i = 0; i < 16; i++) {
    const int ii = iq * 16 + i;
    float gv = 0.f;
#pragma unroll
    for (int u4 = 0; u4 < 16; u4++) {
      const f32x4 g = *(const f32x4*)&Gl[ii][u4 * 4];
      gv += g[0] * Tr[u4][0] + g[1] * Tr[u4][1] + g[2] * Tr[u4][2] + g[3] * Tr[u4][3];
    }
    part += Tl[v][ii] * gv;
  }
  if (iq == 0) {
    float sd = 0.f;
#pragma unroll
    for (int u4 = 0; u4 < 16; u4++) {
      const f32x4 sv = *(const f32x4*)&sl[u4 * 4];
      sd += sv[0] * Tr[u4][0] + sv[1] * Tr[u4][1] + sv[2] * Tr[u4][2] + sv[3] * Tr[u4][3];
    }
    part += cl[v] * (2.f * sd + BF * cl[v]);
  }
  red[tid] = part;
  __syncthreads();
  for (int st = 128; st > 0; st >>= 1) {
    if (tid < st) red[tid] += red[tid + st];
    __syncthreads();
  }
  const float inv = 1.0f / sqrtf(red[0]);

  // ---- compose: Pout[p][k][vo][w] = inv * sum_u Wl[vo][u] * Tl[u][w]
  const int vo = tid >> 2, wq = (tid & 3) * 16;
  f32x4 a16[4];
#pragma unroll
  for (int w4 = 0; w4 < 4; w4++) a16[w4] = (f32x4){0.f, 0.f, 0.f, 0.f};
  for (int u = 0; u < 64; u++) {
    const float w0 = Wl[vo][u];
#pragma unroll
    for (int w4 = 0; w4 < 4; w4++) {
      const f32x4 t = *(const f32x4*)&Tl[u][wq + w4 * 4];
      a16[w4][0] += w0 * t[0]; a16[w4][1] += w0 * t[1];
      a16[w4][2] += w0 * t[2]; a16[w4][3] += w0 * t[3];
    }
  }
  float* po = Pout + (long)(p * KN + kk) * 4096 + vo * 64 + wq;
#pragma unroll
  for (int w4 = 0; w4 < 4; w4++) {
    f32x4 o = a16[w4] * inv;
    *(f32x4*)(po + w4 * 4) = o;
  }

  // ---- bias partial: cpart[p][k][vo] = inv * (cl @ Wl[vo]) + bm[p,k,vo]
  if (tid < 64) {
    float pc = 0.f;
#pragma unroll
    for (int u4 = 0; u4 < 16; u4++) {
      const f32x4 wv = *(const f32x4*)&Wl[tid][u4 * 4];
      pc += wv[0] * cl[u4 * 4] + wv[1] * cl[u4 * 4 + 1] +
            wv[2] * cl[u4 * 4 + 2] + wv[3] * cl[u4 * 4 + 3];
    }
    cpout[(p * KN + kk) * 64 + tid] = inv * pc + bm[(long)(p * KN + kk) * 64 + tid];
  }
}

// ---------- kNorm: sum out-partials, final inv, write scaled Mo/co ----------
__global__ __launch_bounds__(256) void kNorm(const float* __restrict__ Psrc,
                                             const float* __restrict__ csrc,
                                             const float* __restrict__ G,
                                             const float* __restrict__ s,
                                             float* __restrict__ MoS,
                                             float* __restrict__ coS) {
  __shared__ float Tl[64][68], Gl[64][68];
  __shared__ float red[256];
  __shared__ __align__(16) float cl[64], sl[64];
  const int tid = threadIdx.x;
#pragma unroll
  for (int m = 0; m < 16; m++) {
    const int li = m * 256 + tid;
    const int r = li >> 6, cc = li & 63;
    Tl[r][cc] = Psrc[li] + Psrc[4096 + li] + Psrc[8192 + li] + Psrc[12288 + li];
    Gl[r][cc] = G[li];
  }
  if (tid < 64) {
    cl[tid] = csrc[tid] + csrc[64 + tid] + csrc[128 + tid] + csrc[192 + tid];
    sl[tid] = s[tid];
  }
  __syncthreads();

  const int v = tid >> 2, iq = tid & 3;
  f32x4 Tr[16];
#pragma unroll
  for (int u4 = 0; u4 < 16; u4++) Tr[u4] = *(const f32x4*)&Tl[v][u4 * 4];
  float part = 0.f;
  for (int i = 0; i < 16; i++) {
    const int ii = iq * 16 + i;
    float gv = 0.f;
#pragma unroll
    for (int u4 = 0; u4 < 16; u4++) {
      const f32x4 g = *(const f32x4*)&Gl[ii][u4 * 4];
      gv += g[0] * Tr[u4][0] + g[1] * Tr[u4][1] + g[2] * Tr[u4][2] + g[3] * Tr[u4][3];
    }
    part += Tl[v][ii] * gv;
  }
  if (iq == 0) {
    float sd = 0.f;
#pragma unroll
    for (int u4 = 0; u4 < 16; u4++) {
      const f32x4 sv = *(const f32x4*)&sl[u4 * 4];
      sd += sv[0] * Tr[u4][0] + sv[1] * Tr[u4][1] + sv[2] * Tr[u4][2] + sv[3] * Tr[u4][3];
    }
    part += cl[v] * (2.f * sd + BF * cl[v]);
  }
  red[tid] = part;
  __syncthreads();
  for (int st = 128; st > 0; st >>= 1) {
    if (tid < st) red[tid] += red[tid + st];
    __syncthreads();
  }
  const float inv = 1.0f / sqrtf(red[0]);

#pragma unroll
  for (int m = 0; m < 16; m++) {
    const int li = m * 256 + tid;
    MoS[li] = inv * Tl[li >> 6][li & 63];
  }
  if (tid < 64) coS[tid] = inv * cl[tid];
}

// ---------- kApply: out[b][v] = x[b] @ MoS[:,v] + coS[v] --------------------
__global__ __launch_bounds__(256) void kApply(const float* __restrict__ x,
                                              const float* __restrict__ MoS,
                                              const float* __restrict__ coS,
                                              float* __restrict__ out) {
  const int tid = threadIdx.x, lane = tid & 63, vt = tid >> 6;
  const int col = lane & 15, q = lane >> 4;

  bf16x8 bfr[2];
  const float* mr = MoS + (vt * 16 + col) * 64 + q * 8;
  bfr[0] = cvt8(*(const f32x4*)mr, *(const f32x4*)(mr + 4), 1.f);
  bfr[1] = cvt8(*(const f32x4*)(mr + 32), *(const f32x4*)(mr + 36), 1.f);
  const float cf = coS[vt * 16 + col];

  for (int t = 0; t < 16; t++) {
    const int b0 = (blockIdx.x * 16 + t) * 16;
    const float* xr = x + (long)(b0 + col) * 64 + q * 8;
    const bf16x8 a0 = cvt8(*(const f32x4*)xr, *(const f32x4*)(xr + 4), 1.f);
    const bf16x8 a1 = cvt8(*(const f32x4*)(xr + 32), *(const f32x4*)(xr + 36), 1.f);
    f32x4 acc = (f32x4){0.f, 0.f, 0.f, 0.f};
    acc = __builtin_amdgcn_mfma_f32_16x16x32_bf16(a0, bfr[0], acc, 0, 0, 0);
    acc = __builtin_amdgcn_mfma_f32_16x16x32_bf16(a1, bfr[1], acc, 0, 0, 0);
#pragma unroll
    for (int r = 0; r < 4; r++)
      out[(long)(b0 + q * 4 + r) * 64 + vt * 16 + col] = acc[r] + cf;
  }
}

extern "C" void kernel_launch(void* const* d_in, const int* in_sizes, int n_in,
                              void* d_out, int out_size, void* d_ws, size_t ws_size,
                              hipStream_t stream) {
  const float* x    = (const float*)d_in[0];
  const float* Win  = (const float*)d_in[1];
  const float* bin  = (const float*)d_in[2];
  const float* Wmid = (const float*)d_in[3];
  const float* bmid = (const float*)d_in[4];
  const float* Wout = (const float*)d_in[5];
  const float* bout = (const float*)d_in[6];
  float* out = (float*)d_out;
  float* ws  = (float*)d_ws;
  float* Gpart = out;   // 4.26 MB scratch inside d_out; fully overwritten by kApply

  kG   <<<256, 256, 0, stream>>>(x, Gpart);
  kGred<<<65, 256, 0, stream>>>(Gpart, ws + OFF_G, ws + OFF_S);
  kLayer<<<16, 256, 0, stream>>>(Win, bin, Wmid, bmid,
                                 ws + OFF_G, ws + OFF_S, ws + OFF_P0, ws + OFF_C0, 4, 1);
  kLayer<<<16, 256, 0, stream>>>(ws + OFF_P0, ws + OFF_C0, Wmid + 65536, bmid + 1024,
                                 ws + OFF_G, ws + OFF_S, ws + OFF_P1, ws + OFF_C1, 4, 0);
  kLayer<<<16, 256, 0, stream>>>(ws + OFF_P1, ws + OFF_C1, Wmid + 131072, bmid + 2048,
                                 ws + OFF_G, ws + OFF_S, ws + OFF_P0, ws + OFF_C0, 4, 0);
  kLayer<<<4, 256, 0, stream>>>(ws + OFF_P0, ws + OFF_C0, Wout, bout,
                                 ws + OFF_G, ws + OFF_S, ws + OFF_P1, ws + OFF_C1, 1, 0);
  kNorm<<<1, 256, 0, stream>>>(ws + OFF_P1, ws + OFF_C1, ws + OFF_G, ws + OFF_S,
                               ws + OFF_MO, ws + OFF_CO);
  kApply<<<1024, 256, 0, stream>>>(x, ws + OFF_MO, ws + OFF_CO, out);
}

// Round 5
// 266.024 us; speedup vs baseline: 1.1505x; 1.0209x over previous
//
#include <hip/hip_runtime.h>

// GraphNN collapsed to exact affine form:
//   out = (x @ Mo + co) / n_out, all layer norms from G = x^T x and s = colsum(x):
//   n^2 = sum_v T[v].G.T[v] + sum_v c[v]*(2 s.T[v] + B c[v]).
// Round 5: R3 structure (proven, absmax 0.0) + kG at 512 blocks (2/CU latency
// hiding) + register-blocked compose in kLayer. Cooperative-launch fusion
// abandoned (silent launch failure in R4).

#define BF 262144.0f

// ws float offsets
#define OFF_G   0
#define OFF_S   4096
#define OFF_P0  8192
#define OFF_P1  73728
#define OFF_C0  139264
#define OFF_C1  140288
#define OFF_MO  141312
#define OFF_CO  145408

typedef __attribute__((ext_vector_type(8))) short bf16x8;   // 8 bf16 = 4 VGPRs
typedef __attribute__((ext_vector_type(4))) float f32x4;

__device__ __forceinline__ unsigned short f2bf(float f) {
  unsigned u = __builtin_bit_cast(unsigned, f);
  u += 0x7FFF + ((u >> 16) & 1);          // round-to-nearest-even
  return (unsigned short)(u >> 16);
}

__device__ __forceinline__ bf16x8 cvt8(f32x4 a, f32x4 b, float s) {
  bf16x8 t;
#pragma unroll
  for (int j = 0; j < 4; j++) {
    t[j]     = (short)f2bf(a[j] * s);
    t[j + 4] = (short)f2bf(b[j] * s);
  }
  return t;
}

// ---------- kG: per-block partial G = x^T x (bf16 MFMA) + partial colsum ----
// 512 blocks x 256 thr; block handles 512 rows (16 tiles); reg-prefetch.
__global__ __launch_bounds__(256) void kG(const float* __restrict__ x,
                                          float* __restrict__ Gpart) {
  __shared__ __align__(16) unsigned short xts[4][4][16][8];
  __shared__ float sred[256][4];
  const int tid = threadIdx.x;
  const int lane = tid & 63, mt = tid >> 6;
  const int col = lane & 15, q = lane >> 4;
  const int row0 = tid >> 4;            // 0..15
  const int cf0  = (tid & 15) * 4;

  f32x4 acc[4];
#pragma unroll
  for (int nt = 0; nt < 4; nt++) acc[nt] = (f32x4){0.f, 0.f, 0.f, 0.f};
  float s0 = 0.f, s1 = 0.f, s2 = 0.f, s3 = 0.f;

  const float* bx = x + (long)blockIdx.x * 32768;   // 512 rows
  f32x4 r0 = *(const f32x4*)(bx + tid * 4);
  f32x4 r1 = *(const f32x4*)(bx + 1024 + tid * 4);

  for (int c = 0; c < 16; c++) {
    __syncthreads();                    // prev MFMA done reading LDS
    s0 += r0[0] + r1[0]; s1 += r0[1] + r1[1];
    s2 += r0[2] + r1[2]; s3 += r0[3] + r1[3];
#pragma unroll
    for (int j = 0; j < 4; j++) {
      const int cf = cf0 + j;
      xts[cf >> 4][row0 >> 3][cf & 15][row0 & 7]        = f2bf(r0[j]);
      xts[cf >> 4][2 + (row0 >> 3)][cf & 15][row0 & 7]  = f2bf(r1[j]);
    }
    f32x4 r0n = r0, r1n = r1;
    if (c < 15) {
      r0n = *(const f32x4*)(bx + (c + 1) * 2048 + tid * 4);
      r1n = *(const f32x4*)(bx + (c + 1) * 2048 + 1024 + tid * 4);
    }
    __syncthreads();                    // tile ready
    const bf16x8 af = *(const bf16x8*)xts[mt][q][col];
#pragma unroll
    for (int nt = 0; nt < 4; nt++) {
      const bf16x8 bfr = *(const bf16x8*)xts[nt][q][col];
      acc[nt] = __builtin_amdgcn_mfma_f32_16x16x32_bf16(af, bfr, acc[nt], 0, 0, 0);
    }
    r0 = r0n; r1 = r1n;
  }

  float* myp = Gpart + (long)blockIdx.x * 4160;
#pragma unroll
  for (int nt = 0; nt < 4; nt++)
#pragma unroll
    for (int r = 0; r < 4; r++)
      myp[(mt * 16 + q * 4 + r) * 64 + nt * 16 + col] = acc[nt][r];

  sred[tid][0] = s0; sred[tid][1] = s1; sred[tid][2] = s2; sred[tid][3] = s3;
  __syncthreads();
  if (tid < 64) {
    float t = 0.f;
#pragma unroll
    for (int k2 = 0; k2 < 16; k2++) t += sred[(tid >> 2) + 16 * k2][tid & 3];
    myp[4096 + tid] = t;
  }
}

// ---------- kGred: reduce 512 partials -> G, s (coalesced) ------------------
__global__ __launch_bounds__(256) void kGred(const float* __restrict__ Gpart,
                                             float* __restrict__ G,
                                             float* __restrict__ s) {
  __shared__ float red[4][64];
  const int tid = threadIdx.x;
  const int e = blockIdx.x * 64 + (tid & 63);
  const int quarter = tid >> 6;
  float acc = 0.f;
#pragma unroll 4
  for (int j = 0; j < 128; j++)
    acc += Gpart[(long)(quarter * 128 + j) * 4160 + e];
  red[quarter][tid & 63] = acc;
  __syncthreads();
  if (tid < 64) {
    const float t = red[0][tid] + red[1][tid] + red[2][tid] + red[3][tid];
    const int ee = blockIdx.x * 64 + tid;
    if (ee < 4096) G[ee] = t;
    else           s[ee - 4096] = t;
  }
}

// ---------- kLayer: one structural layer of the exact fp32 affine chain -----
// Block (p,k): Tl = (first ? Win[p] : sum_p' Pprev[p'][p]); computes inv_p;
// writes Pout[p][k] = inv * W_pk @ Tl  and  cpart[p][k] (no atomics).
__global__ __launch_bounds__(256) void kLayer(const float* __restrict__ Tsrc,
                                              const float* __restrict__ csrc,
                                              const float* __restrict__ Wm,
                                              const float* __restrict__ bm,
                                              const float* __restrict__ G,
                                              const float* __restrict__ s,
                                              float* __restrict__ Pout,
                                              float* __restrict__ cpout,
                                              const int KN, const int first) {
  __shared__ float Tl[64][68], Gl[64][68], Wl[64][68];
  __shared__ float red[256];
  __shared__ __align__(16) float cl[64], sl[64];
  const int tid = threadIdx.x;
  const int p = blockIdx.x / KN, kk = blockIdx.x % KN;

#pragma unroll
  for (int m = 0; m < 16; m++) {
    const int li = m * 256 + tid;
    const int r = li >> 6, cc = li & 63;
    float tv;
    if (first) tv = Tsrc[p * 4096 + li];
    else tv = Tsrc[p * 4096 + li] + Tsrc[(4 + p) * 4096 + li] +
              Tsrc[(8 + p) * 4096 + li] + Tsrc[(12 + p) * 4096 + li];
    Tl[r][cc] = tv;
    Gl[r][cc] = G[li];
    Wl[r][cc] = Wm[(long)(p * KN + kk) * 4096 + li];
  }
  if (tid < 64) {
    float cv;
    if (first) cv = csrc[p * 64 + tid];
    else cv = csrc[p * 64 + tid] + csrc[(4 + p) * 64 + tid] +
              csrc[(8 + p) * 64 + tid] + csrc[(12 + p) * 64 + tid];
    cl[tid] = cv;
    sl[tid] = s[tid];
  }
  __syncthreads();

  // ---- n^2 quadratic form; thread (v=tid>>2, iq=tid&3), T-row in registers
  const int v = tid >> 2, iq = tid & 3;
  {
    f32x4 Tr[16];
#pragma unroll
    for (int u4 = 0; u4 < 16; u4++) Tr[u4] = *(const f32x4*)&Tl[v][u4 * 4];
    float part = 0.f;
    for (int i = 0; i < 16; i++) {
      const int ii = iq * 16 + i;
      float gv = 0.f;
#pragma unroll
      for (int u4 = 0; u4 < 16; u4++) {
        const f32x4 g = *(const f32x4*)&Gl[ii][u4 * 4];
        gv += g[0] * Tr[u4][0] + g[1] * Tr[u4][1] + g[2] * Tr[u4][2] + g[3] * Tr[u4][3];
      }
      part += Tl[v][ii] * gv;
    }
    if (iq == 0) {
      float sd = 0.f;
#pragma unroll
      for (int u4 = 0; u4 < 16; u4++) {
        const f32x4 sv = *(const f32x4*)&sl[u4 * 4];
        sd += sv[0] * Tr[u4][0] + sv[1] * Tr[u4][1] + sv[2] * Tr[u4][2] + sv[3] * Tr[u4][3];
      }
      part += cl[v] * (2.f * sd + BF * cl[v]);
    }
    red[tid] = part;
  }
  __syncthreads();
  for (int st = 128; st > 0; st >>= 1) {
    if (tid < st) red[tid] += red[tid + st];
    __syncthreads();
  }
  const float inv = 1.0f / sqrtf(red[0]);

  // ---- compose: Pout[p][k] = inv * (Wl @ Tl); register-blocked 2vo x 8w
  {
    const int vo = tid >> 3;            // rows vo and vo+32
    const int w8 = (tid & 7) * 8;
    float a0[8], a1[8];
#pragma unroll
    for (int j = 0; j < 8; j++) { a0[j] = 0.f; a1[j] = 0.f; }
    for (int ub = 0; ub < 4; ub++) {
      f32x4 wr0[4], wr1[4];
#pragma unroll
      for (int j = 0; j < 4; j++) {
        wr0[j] = *(const f32x4*)&Wl[vo][ub * 16 + j * 4];
        wr1[j] = *(const f32x4*)&Wl[vo + 32][ub * 16 + j * 4];
      }
#pragma unroll
      for (int uu = 0; uu < 16; uu++) {
        const int u = ub * 16 + uu;
        const f32x4 t0 = *(const f32x4*)&Tl[u][w8];
        const f32x4 t1 = *(const f32x4*)&Tl[u][w8 + 4];
        const float w0 = wr0[uu >> 2][uu & 3];
        const float w1 = wr1[uu >> 2][uu & 3];
#pragma unroll
        for (int j = 0; j < 4; j++) {
          a0[j]     += w0 * t0[j]; a0[j + 4] += w0 * t1[j];
          a1[j]     += w1 * t0[j]; a1[j + 4] += w1 * t1[j];
        }
      }
    }
    float* po = Pout + (long)(p * KN + kk) * 4096;
    f32x4 o;
#pragma unroll
    for (int j = 0; j < 4; j++) o[j] = inv * a0[j];
    *(f32x4*)(po + vo * 64 + w8) = o;
#pragma unroll
    for (int j = 0; j < 4; j++) o[j] = inv * a0[j + 4];
    *(f32x4*)(po + vo * 64 + w8 + 4) = o;
#pragma unroll
    for (int j = 0; j < 4; j++) o[j] = inv * a1[j];
    *(f32x4*)(po + (vo + 32) * 64 + w8) = o;
#pragma unroll
    for (int j = 0; j < 4; j++) o[j] = inv * a1[j + 4];
    *(f32x4*)(po + (vo + 32) * 64 + w8 + 4) = o;
  }

  // ---- bias partial: cpart[p][k][vo] = inv * (cl @ Wl[vo]) + bm[p,k,vo]
  if (tid < 64) {
    float pc = 0.f;
#pragma unroll
    for (int u4 = 0; u4 < 16; u4++) {
      const f32x4 wv = *(const f32x4*)&Wl[tid][u4 * 4];
      pc += wv[0] * cl[u4 * 4] + wv[1] * cl[u4 * 4 + 1] +
            wv[2] * cl[u4 * 4 + 2] + wv[3] * cl[u4 * 4 + 3];
    }
    cpout[(p * KN + kk) * 64 + tid] = inv * pc + bm[(long)(p * KN + kk) * 64 + tid];
  }
}

// ---------- kNorm: sum out-partials, final inv, write scaled Mo/co ----------
__global__ __launch_bounds__(256) void kNorm(const float* __restrict__ Psrc,
                                             const float* __restrict__ csrc,
                                             const float* __restrict__ G,
                                             const float* __restrict__ s,
                                             float* __restrict__ MoS,
                                             float* __restrict__ coS) {
  __shared__ float Tl[64][68], Gl[64][68];
  __shared__ float red[256];
  __shared__ __align__(16) float cl[64], sl[64];
  const int tid = threadIdx.x;
#pragma unroll
  for (int m = 0; m < 16; m++) {
    const int li = m * 256 + tid;
    const int r = li >> 6, cc = li & 63;
    Tl[r][cc] = Psrc[li] + Psrc[4096 + li] + Psrc[8192 + li] + Psrc[12288 + li];
    Gl[r][cc] = G[li];
  }
  if (tid < 64) {
    cl[tid] = csrc[tid] + csrc[64 + tid] + csrc[128 + tid] + csrc[192 + tid];
    sl[tid] = s[tid];
  }
  __syncthreads();

  const int v = tid >> 2, iq = tid & 3;
  f32x4 Tr[16];
#pragma unroll
  for (int u4 = 0; u4 < 16; u4++) Tr[u4] = *(const f32x4*)&Tl[v][u4 * 4];
  float part = 0.f;
  for (int i = 0; i < 16; i++) {
    const int ii = iq * 16 + i;
    float gv = 0.f;
#pragma unroll
    for (int u4 = 0; u4 < 16; u4++) {
      const f32x4 g = *(const f32x4*)&Gl[ii][u4 * 4];
      gv += g[0] * Tr[u4][0] + g[1] * Tr[u4][1] + g[2] * Tr[u4][2] + g[3] * Tr[u4][3];
    }
    part += Tl[v][ii] * gv;
  }
  if (iq == 0) {
    float sd = 0.f;
#pragma unroll
    for (int u4 = 0; u4 < 16; u4++) {
      const f32x4 sv = *(const f32x4*)&sl[u4 * 4];
      sd += sv[0] * Tr[u4][0] + sv[1] * Tr[u4][1] + sv[2] * Tr[u4][2] + sv[3] * Tr[u4][3];
    }
    part += cl[v] * (2.f * sd + BF * cl[v]);
  }
  red[tid] = part;
  __syncthreads();
  for (int st = 128; st > 0; st >>= 1) {
    if (tid < st) red[tid] += red[tid + st];
    __syncthreads();
  }
  const float inv = 1.0f / sqrtf(red[0]);

#pragma unroll
  for (int m = 0; m < 16; m++) {
    const int li = m * 256 + tid;
    MoS[li] = inv * Tl[li >> 6][li & 63];
  }
  if (tid < 64) coS[tid] = inv * cl[tid];
}

// ---------- kApply: out[b][v] = x[b] @ MoS[:,v] + coS[v] --------------------
__global__ __launch_bounds__(256) void kApply(const float* __restrict__ x,
                                              const float* __restrict__ MoS,
                                              const float* __restrict__ coS,
                                              float* __restrict__ out) {
  const int tid = threadIdx.x, lane = tid & 63, vt = tid >> 6;
  const int col = lane & 15, q = lane >> 4;

  bf16x8 bfr[2];
  const float* mr = MoS + (vt * 16 + col) * 64 + q * 8;
  bfr[0] = cvt8(*(const f32x4*)mr, *(const f32x4*)(mr + 4), 1.f);
  bfr[1] = cvt8(*(const f32x4*)(mr + 32), *(const f32x4*)(mr + 36), 1.f);
  const float cf = coS[vt * 16 + col];

  for (int t = 0; t < 16; t++) {
    const int b0 = (blockIdx.x * 16 + t) * 16;
    const float* xr = x + (long)(b0 + col) * 64 + q * 8;
    const bf16x8 a0 = cvt8(*(const f32x4*)xr, *(const f32x4*)(xr + 4), 1.f);
    const bf16x8 a1 = cvt8(*(const f32x4*)(xr + 32), *(const f32x4*)(xr + 36), 1.f);
    f32x4 acc = (f32x4){0.f, 0.f, 0.f, 0.f};
    acc = __builtin_amdgcn_mfma_f32_16x16x32_bf16(a0, bfr[0], acc, 0, 0, 0);
    acc = __builtin_amdgcn_mfma_f32_16x16x32_bf16(a1, bfr[1], acc, 0, 0, 0);
#pragma unroll
    for (int r = 0; r < 4; r++)
      out[(long)(b0 + q * 4 + r) * 64 + vt * 16 + col] = acc[r] + cf;
  }
}

extern "C" void kernel_launch(void* const* d_in, const int* in_sizes, int n_in,
                              void* d_out, int out_size, void* d_ws, size_t ws_size,
                              hipStream_t stream) {
  const float* x    = (const float*)d_in[0];
  const float* Win  = (const float*)d_in[1];
  const float* bin  = (const float*)d_in[2];
  const float* Wmid = (const float*)d_in[3];
  const float* bmid = (const float*)d_in[4];
  const float* Wout = (const float*)d_in[5];
  const float* bout = (const float*)d_in[6];
  float* out = (float*)d_out;
  float* ws  = (float*)d_ws;
  float* Gpart = out;   // 8.5 MB scratch inside d_out; fully overwritten by kApply

  kG   <<<512, 256, 0, stream>>>(x, Gpart);
  kGred<<<65, 256, 0, stream>>>(Gpart, ws + OFF_G, ws + OFF_S);
  kLayer<<<16, 256, 0, stream>>>(Win, bin, Wmid, bmid,
                                 ws + OFF_G, ws + OFF_S, ws + OFF_P0, ws + OFF_C0, 4, 1);
  kLayer<<<16, 256, 0, stream>>>(ws + OFF_P0, ws + OFF_C0, Wmid + 65536, bmid + 1024,
                                 ws + OFF_G, ws + OFF_S, ws + OFF_P1, ws + OFF_C1, 4, 0);
  kLayer<<<16, 256, 0, stream>>>(ws + OFF_P1, ws + OFF_C1, Wmid + 131072, bmid + 2048,
                                 ws + OFF_G, ws + OFF_S, ws + OFF_P0, ws + OFF_C0, 4, 0);
  kLayer<<<4, 256, 0, stream>>>(ws + OFF_P0, ws + OFF_C0, Wout, bout,
                                 ws + OFF_G, ws + OFF_S, ws + OFF_P1, ws + OFF_C1, 1, 0);
  kNorm<<<1, 256, 0, stream>>>(ws + OFF_P1, ws + OFF_C1, ws + OFF_G, ws + OFF_S,
                               ws + OFF_MO, ws + OFF_CO);
  kApply<<<1024, 256, 0, stream>>>(x, ws + OFF_MO, ws + OFF_CO, out);
}

// Round 6
// 233.936 us; speedup vs baseline: 1.3084x; 1.1372x over previous
//
#include <hip/hip_runtime.h>

// GraphNN collapsed to exact affine form:
//   out = (x @ Mo + co) / n_out; norms from G = x^T x, s = colsum(x):
//   n^2 = sum_{i,u} G[i][u]*H[i][u] + sum_v c[v]*(2 s.T[v] + B c[v]),  H = T^T T.
// Round 6: chain kernels (kLayer/kNorm) moved to split-bf16 MFMA:
//   T = Th + Tl (2-term bf16 split), H and W@T via 3-product MFMA (drop lo*lo),
//   G consumed via per-lane fp32 register prefetch matching MFMA D-layout.
// Bias/c-chain stays exact fp32. kG / kGred / kApply identical to R5 (proven).

#define BF 262144.0f

// ws float offsets
#define OFF_G   0
#define OFF_S   4096
#define OFF_P0  8192
#define OFF_P1  73728
#define OFF_C0  139264
#define OFF_C1  140288
#define OFF_MO  141312
#define OFF_CO  145408

typedef __attribute__((ext_vector_type(8))) short bf16x8;   // 8 bf16 = 4 VGPRs
typedef __attribute__((ext_vector_type(4))) float f32x4;

__device__ __forceinline__ unsigned short f2bf(float f) {
  unsigned u = __builtin_bit_cast(unsigned, f);
  u += 0x7FFF + ((u >> 16) & 1);          // round-to-nearest-even
  return (unsigned short)(u >> 16);
}
__device__ __forceinline__ float bf2f(unsigned short h) {
  unsigned u = ((unsigned)h) << 16;
  return __builtin_bit_cast(float, u);
}

__device__ __forceinline__ bf16x8 cvt8(f32x4 a, f32x4 b, float s) {
  bf16x8 t;
#pragma unroll
  for (int j = 0; j < 4; j++) {
    t[j]     = (short)f2bf(a[j] * s);
    t[j + 4] = (short)f2bf(b[j] * s);
  }
  return t;
}

// ---------- kG: per-block partial G = x^T x (bf16 MFMA) + partial colsum ----
__global__ __launch_bounds__(256) void kG(const float* __restrict__ x,
                                          float* __restrict__ Gpart) {
  __shared__ __align__(16) unsigned short xts[4][4][16][8];
  __shared__ float sred[256][4];
  const int tid = threadIdx.x;
  const int lane = tid & 63, mt = tid >> 6;
  const int col = lane & 15, q = lane >> 4;
  const int row0 = tid >> 4;
  const int cf0  = (tid & 15) * 4;

  f32x4 acc[4];
#pragma unroll
  for (int nt = 0; nt < 4; nt++) acc[nt] = (f32x4){0.f, 0.f, 0.f, 0.f};
  float s0 = 0.f, s1 = 0.f, s2 = 0.f, s3 = 0.f;

  const float* bx = x + (long)blockIdx.x * 32768;   // 512 rows
  f32x4 r0 = *(const f32x4*)(bx + tid * 4);
  f32x4 r1 = *(const f32x4*)(bx + 1024 + tid * 4);

  for (int c = 0; c < 16; c++) {
    __syncthreads();
    s0 += r0[0] + r1[0]; s1 += r0[1] + r1[1];
    s2 += r0[2] + r1[2]; s3 += r0[3] + r1[3];
#pragma unroll
    for (int j = 0; j < 4; j++) {
      const int cf = cf0 + j;
      xts[cf >> 4][row0 >> 3][cf & 15][row0 & 7]        = f2bf(r0[j]);
      xts[cf >> 4][2 + (row0 >> 3)][cf & 15][row0 & 7]  = f2bf(r1[j]);
    }
    f32x4 r0n = r0, r1n = r1;
    if (c < 15) {
      r0n = *(const f32x4*)(bx + (c + 1) * 2048 + tid * 4);
      r1n = *(const f32x4*)(bx + (c + 1) * 2048 + 1024 + tid * 4);
    }
    __syncthreads();
    const bf16x8 af = *(const bf16x8*)xts[mt][q][col];
#pragma unroll
    for (int nt = 0; nt < 4; nt++) {
      const bf16x8 bfr = *(const bf16x8*)xts[nt][q][col];
      acc[nt] = __builtin_amdgcn_mfma_f32_16x16x32_bf16(af, bfr, acc[nt], 0, 0, 0);
    }
    r0 = r0n; r1 = r1n;
  }

  float* myp = Gpart + (long)blockIdx.x * 4160;
#pragma unroll
  for (int nt = 0; nt < 4; nt++)
#pragma unroll
    for (int r = 0; r < 4; r++)
      myp[(mt * 16 + q * 4 + r) * 64 + nt * 16 + col] = acc[nt][r];

  sred[tid][0] = s0; sred[tid][1] = s1; sred[tid][2] = s2; sred[tid][3] = s3;
  __syncthreads();
  if (tid < 64) {
    float t = 0.f;
#pragma unroll
    for (int k2 = 0; k2 < 16; k2++) t += sred[(tid >> 2) + 16 * k2][tid & 3];
    myp[4096 + tid] = t;
  }
}

// ---------- kGred: reduce 512 partials -> G, s (coalesced) ------------------
__global__ __launch_bounds__(256) void kGred(const float* __restrict__ Gpart,
                                             float* __restrict__ G,
                                             float* __restrict__ s) {
  __shared__ float red[4][64];
  const int tid = threadIdx.x;
  const int e = blockIdx.x * 64 + (tid & 63);
  const int quarter = tid >> 6;
  float acc = 0.f;
#pragma unroll 4
  for (int j = 0; j < 128; j++)
    acc += Gpart[(long)(quarter * 128 + j) * 4160 + e];
  red[quarter][tid & 63] = acc;
  __syncthreads();
  if (tid < 64) {
    const float t = red[0][tid] + red[1][tid] + red[2][tid] + red[3][tid];
    const int ee = blockIdx.x * 64 + tid;
    if (ee < 4096) G[ee] = t;
    else           s[ee - 4096] = t;
  }
}

// ---------- kLayer: one structural layer, split-bf16 MFMA -------------------
// Block (p,k): Tf = (first ? Win[p] : sum_p' Pprev[p'][p]); inv_p from
// q = sum G.*(T^T T) + c-terms;  Pout[p*KN+k] = inv * (W_pk @ Tf) via MFMA.
__global__ __launch_bounds__(256) void kLayer(const float* __restrict__ Tsrc,
                                              const float* __restrict__ csrc,
                                              const float* __restrict__ Wm,
                                              const float* __restrict__ bm,
                                              const float* __restrict__ G,
                                              const float* __restrict__ s,
                                              float* __restrict__ Pout,
                                              float* __restrict__ cpout,
                                              const int KN, const int first) {
  __shared__ float Tf[64][68];
  __shared__ __align__(16) unsigned short Tth[64][68], Ttl[64][68];
  __shared__ __align__(16) unsigned short Wh[64][68], Wlo[64][68];
  __shared__ float red[256];
  __shared__ __align__(16) float cl[64], sl[64];
  const int tid = threadIdx.x;
  const int p = blockIdx.x / KN, kk = blockIdx.x % KN;
  const int lane = tid & 63, it = tid >> 6;   // wave = i-tile (q) / vo-tile (compose)
  const int col = lane & 15, quad = lane >> 4;

  // G prefetch into regs, matching MFMA D-layout: D[m=i][n=u]
  float Greg[4][4];
#pragma unroll
  for (int ut = 0; ut < 4; ut++)
#pragma unroll
    for (int r = 0; r < 4; r++)
      Greg[ut][r] = G[(it * 16 + quad * 4 + r) * 64 + ut * 16 + col];

  // ---- phase 1: build Tf (fp32), split W -> Wh/Wlo, load cl/sl
#pragma unroll
  for (int m = 0; m < 16; m++) {
    const int li = m * 256 + tid;
    const int r = li >> 6, cc = li & 63;
    float tv;
    if (first) tv = Tsrc[p * 4096 + li];
    else tv = Tsrc[p * 4096 + li] + Tsrc[(4 + p) * 4096 + li] +
              Tsrc[(8 + p) * 4096 + li] + Tsrc[(12 + p) * 4096 + li];
    Tf[r][cc] = tv;
    const float wv = Wm[(long)(p * KN + kk) * 4096 + li];
    const unsigned short wh = f2bf(wv);
    Wh[r][cc] = wh;
    Wlo[r][cc] = f2bf(wv - bf2f(wh));
  }
  if (tid < 64) {
    float cv;
    if (first) cv = csrc[p * 64 + tid];
    else cv = csrc[p * 64 + tid] + csrc[(4 + p) * 64 + tid] +
              csrc[(8 + p) * 64 + tid] + csrc[(12 + p) * 64 + tid];
    cl[tid] = cv;
    sl[tid] = s[tid];
  }
  __syncthreads();

  // ---- phase 2: split+transpose Tf -> Tth/Ttl  (Tt[w][v] = T[v][w])
  {
    const int tc = tid >> 2;            // Tt row (= Tf column)
    const int rb = (tid & 3) * 16;
#pragma unroll
    for (int j = 0; j < 16; j++) {
      const float tv = Tf[rb + j][tc];
      const unsigned short h = f2bf(tv);
      Tth[tc][rb + j] = h;
      Ttl[tc][rb + j] = f2bf(tv - bf2f(h));
    }
  }
  __syncthreads();

  // ---- phase 3: q = sum G .* (T^T T) + c-terms
  float qp = 0.f;
  {
    f32x4 dq[4];
#pragma unroll
    for (int ut = 0; ut < 4; ut++) dq[ut] = (f32x4){0.f, 0.f, 0.f, 0.f};
#pragma unroll
    for (int ks = 0; ks < 2; ks++) {
      const bf16x8 ah = *(const bf16x8*)&Tth[it * 16 + col][ks * 32 + quad * 8];
      const bf16x8 al = *(const bf16x8*)&Ttl[it * 16 + col][ks * 32 + quad * 8];
#pragma unroll
      for (int ut = 0; ut < 4; ut++) {
        const bf16x8 bh = *(const bf16x8*)&Tth[ut * 16 + col][ks * 32 + quad * 8];
        const bf16x8 bl = *(const bf16x8*)&Ttl[ut * 16 + col][ks * 32 + quad * 8];
        dq[ut] = __builtin_amdgcn_mfma_f32_16x16x32_bf16(ah, bh, dq[ut], 0, 0, 0);
        dq[ut] = __builtin_amdgcn_mfma_f32_16x16x32_bf16(ah, bl, dq[ut], 0, 0, 0);
        dq[ut] = __builtin_amdgcn_mfma_f32_16x16x32_bf16(al, bh, dq[ut], 0, 0, 0);
      }
    }
#pragma unroll
    for (int ut = 0; ut < 4; ut++)
#pragma unroll
      for (int r = 0; r < 4; r++)
        qp += dq[ut][r] * Greg[ut][r];
  }
  if (tid < 64) {       // c-terms: v = tid
    float sd = 0.f;
#pragma unroll
    for (int u4 = 0; u4 < 16; u4++) {
      const f32x4 tv = *(const f32x4*)&Tf[tid][u4 * 4];
      const f32x4 sv = *(const f32x4*)&sl[u4 * 4];
      sd += sv[0] * tv[0] + sv[1] * tv[1] + sv[2] * tv[2] + sv[3] * tv[3];
    }
    qp += cl[tid] * (2.f * sd + BF * cl[tid]);
  }
  red[tid] = qp;
  __syncthreads();
  for (int st = 128; st > 0; st >>= 1) {
    if (tid < st) red[tid] += red[tid + st];
    __syncthreads();
  }
  const float inv = 1.0f / sqrtf(red[0]);

  // ---- phase 4: compose Pout = inv * (W @ T) via split MFMA
  {
    f32x4 dc[4];
#pragma unroll
    for (int nt = 0; nt < 4; nt++) dc[nt] = (f32x4){0.f, 0.f, 0.f, 0.f};
#pragma unroll
    for (int ks = 0; ks < 2; ks++) {
      const bf16x8 awh = *(const bf16x8*)&Wh[it * 16 + col][ks * 32 + quad * 8];
      const bf16x8 awl = *(const bf16x8*)&Wlo[it * 16 + col][ks * 32 + quad * 8];
#pragma unroll
      for (int nt = 0; nt < 4; nt++) {
        const bf16x8 bh = *(const bf16x8*)&Tth[nt * 16 + col][ks * 32 + quad * 8];
        const bf16x8 bl = *(const bf16x8*)&Ttl[nt * 16 + col][ks * 32 + quad * 8];
        dc[nt] = __builtin_amdgcn_mfma_f32_16x16x32_bf16(awh, bh, dc[nt], 0, 0, 0);
        dc[nt] = __builtin_amdgcn_mfma_f32_16x16x32_bf16(awh, bl, dc[nt], 0, 0, 0);
        dc[nt] = __builtin_amdgcn_mfma_f32_16x16x32_bf16(awl, bh, dc[nt], 0, 0, 0);
      }
    }
    float* po = Pout + (long)(p * KN + kk) * 4096;
#pragma unroll
    for (int nt = 0; nt < 4; nt++)
#pragma unroll
      for (int r = 0; r < 4; r++)
        po[(it * 16 + quad * 4 + r) * 64 + nt * 16 + col] = inv * dc[nt][r];
  }

  // ---- bias chain (exact fp32): cpart = inv * (cl @ W^T) + bm
  if (tid < 64) {
    const float* wg = Wm + (long)(p * KN + kk) * 4096 + tid * 64;
    float pc = 0.f;
#pragma unroll
    for (int u4 = 0; u4 < 16; u4++) {
      const f32x4 wv = *(const f32x4*)(wg + u4 * 4);
      pc += wv[0] * cl[u4 * 4] + wv[1] * cl[u4 * 4 + 1] +
            wv[2] * cl[u4 * 4 + 2] + wv[3] * cl[u4 * 4 + 3];
    }
    cpout[(p * KN + kk) * 64 + tid] = inv * pc + bm[(long)(p * KN + kk) * 64 + tid];
  }
}

// ---------- kNorm: final norm via split MFMA; write scaled Mo/co ------------
__global__ __launch_bounds__(256) void kNorm(const float* __restrict__ Psrc,
                                             const float* __restrict__ csrc,
                                             const float* __restrict__ G,
                                             const float* __restrict__ s,
                                             float* __restrict__ MoS,
                                             float* __restrict__ coS) {
  __shared__ float Tf[64][68];
  __shared__ __align__(16) unsigned short Tth[64][68], Ttl[64][68];
  __shared__ float red[256];
  __shared__ __align__(16) float cl[64], sl[64];
  const int tid = threadIdx.x;
  const int lane = tid & 63, it = tid >> 6;
  const int col = lane & 15, quad = lane >> 4;

  float Greg[4][4];
#pragma unroll
  for (int ut = 0; ut < 4; ut++)
#pragma unroll
    for (int r = 0; r < 4; r++)
      Greg[ut][r] = G[(it * 16 + quad * 4 + r) * 64 + ut * 16 + col];

#pragma unroll
  for (int m = 0; m < 16; m++) {
    const int li = m * 256 + tid;
    Tf[li >> 6][li & 63] = Psrc[li] + Psrc[4096 + li] + Psrc[8192 + li] + Psrc[12288 + li];
  }
  if (tid < 64) {
    cl[tid] = csrc[tid] + csrc[64 + tid] + csrc[128 + tid] + csrc[192 + tid];
    sl[tid] = s[tid];
  }
  __syncthreads();

  {
    const int tc = tid >> 2;
    const int rb = (tid & 3) * 16;
#pragma unroll
    for (int j = 0; j < 16; j++) {
      const float tv = Tf[rb + j][tc];
      const unsigned short h = f2bf(tv);
      Tth[tc][rb + j] = h;
      Ttl[tc][rb + j] = f2bf(tv - bf2f(h));
    }
  }
  __syncthreads();

  float qp = 0.f;
  {
    f32x4 dq[4];
#pragma unroll
    for (int ut = 0; ut < 4; ut++) dq[ut] = (f32x4){0.f, 0.f, 0.f, 0.f};
#pragma unroll
    for (int ks = 0; ks < 2; ks++) {
      const bf16x8 ah = *(const bf16x8*)&Tth[it * 16 + col][ks * 32 + quad * 8];
      const bf16x8 al = *(const bf16x8*)&Ttl[it * 16 + col][ks * 32 + quad * 8];
#pragma unroll
      for (int ut = 0; ut < 4; ut++) {
        const bf16x8 bh = *(const bf16x8*)&Tth[ut * 16 + col][ks * 32 + quad * 8];
        const bf16x8 bl = *(const bf16x8*)&Ttl[ut * 16 + col][ks * 32 + quad * 8];
        dq[ut] = __builtin_amdgcn_mfma_f32_16x16x32_bf16(ah, bh, dq[ut], 0, 0, 0);
        dq[ut] = __builtin_amdgcn_mfma_f32_16x16x32_bf16(ah, bl, dq[ut], 0, 0, 0);
        dq[ut] = __builtin_amdgcn_mfma_f32_16x16x32_bf16(al, bh, dq[ut], 0, 0, 0);
      }
    }
#pragma unroll
    for (int ut = 0; ut < 4; ut++)
#pragma unroll
      for (int r = 0; r < 4; r++)
        qp += dq[ut][r] * Greg[ut][r];
  }
  if (tid < 64) {
    float sd = 0.f;
#pragma unroll
    for (int u4 = 0; u4 < 16; u4++) {
      const f32x4 tv = *(const f32x4*)&Tf[tid][u4 * 4];
      const f32x4 sv = *(const f32x4*)&sl[u4 * 4];
      sd += sv[0] * tv[0] + sv[1] * tv[1] + sv[2] * tv[2] + sv[3] * tv[3];
    }
    qp += cl[tid] * (2.f * sd + BF * cl[tid]);
  }
  red[tid] = qp;
  __syncthreads();
  for (int st = 128; st > 0; st >>= 1) {
    if (tid < st) red[tid] += red[tid + st];
    __syncthreads();
  }
  const float inv = 1.0f / sqrtf(red[0]);

#pragma unroll
  for (int m = 0; m < 16; m++) {
    const int li = m * 256 + tid;
    MoS[li] = inv * Tf[li >> 6][li & 63];
  }
  if (tid < 64) coS[tid] = inv * cl[tid];
}

// ---------- kApply: out[b][v] = x[b] @ MoS[:,v] + coS[v] --------------------
__global__ __launch_bounds__(256) void kApply(const float* __restrict__ x,
                                              const float* __restrict__ MoS,
                                              const float* __restrict__ coS,
                                              float* __restrict__ out) {
  const int tid = threadIdx.x, lane = tid & 63, vt = tid >> 6;
  const int col = lane & 15, q = lane >> 4;

  bf16x8 bfr[2];
  const float* mr = MoS + (vt * 16 + col) * 64 + q * 8;
  bfr[0] = cvt8(*(const f32x4*)mr, *(const f32x4*)(mr + 4), 1.f);
  bfr[1] = cvt8(*(const f32x4*)(mr + 32), *(const f32x4*)(mr + 36), 1.f);
  const float cf = coS[vt * 16 + col];

  for (int t = 0; t < 16; t++) {
    const int b0 = (blockIdx.x * 16 + t) * 16;
    const float* xr = x + (long)(b0 + col) * 64 + q * 8;
    const bf16x8 a0 = cvt8(*(const f32x4*)xr, *(const f32x4*)(xr + 4), 1.f);
    const bf16x8 a1 = cvt8(*(const f32x4*)(xr + 32), *(const f32x4*)(xr + 36), 1.f);
    f32x4 acc = (f32x4){0.f, 0.f, 0.f, 0.f};
    acc = __builtin_amdgcn_mfma_f32_16x16x32_bf16(a0, bfr[0], acc, 0, 0, 0);
    acc = __builtin_amdgcn_mfma_f32_16x16x32_bf16(a1, bfr[1], acc, 0, 0, 0);
#pragma unroll
    for (int r = 0; r < 4; r++)
      out[(long)(b0 + q * 4 + r) * 64 + vt * 16 + col] = acc[r] + cf;
  }
}

extern "C" void kernel_launch(void* const* d_in, const int* in_sizes, int n_in,
                              void* d_out, int out_size, void* d_ws, size_t ws_size,
                              hipStream_t stream) {
  const float* x    = (const float*)d_in[0];
  const float* Win  = (const float*)d_in[1];
  const float* bin  = (const float*)d_in[2];
  const float* Wmid = (const float*)d_in[3];
  const float* bmid = (const float*)d_in[4];
  const float* Wout = (const float*)d_in[5];
  const float* bout = (const float*)d_in[6];
  float* out = (float*)d_out;
  float* ws  = (float*)d_ws;
  float* Gpart = out;   // 8.5 MB scratch inside d_out; fully overwritten by kApply

  kG   <<<512, 256, 0, stream>>>(x, Gpart);
  kGred<<<65, 256, 0, stream>>>(Gpart, ws + OFF_G, ws + OFF_S);
  kLayer<<<16, 256, 0, stream>>>(Win, bin, Wmid, bmid,
                                 ws + OFF_G, ws + OFF_S, ws + OFF_P0, ws + OFF_C0, 4, 1);
  kLayer<<<16, 256, 0, stream>>>(ws + OFF_P0, ws + OFF_C0, Wmid + 65536, bmid + 1024,
                                 ws + OFF_G, ws + OFF_S, ws + OFF_P1, ws + OFF_C1, 4, 0);
  kLayer<<<16, 256, 0, stream>>>(ws + OFF_P1, ws + OFF_C1, Wmid + 131072, bmid + 2048,
                                 ws + OFF_G, ws + OFF_S, ws + OFF_P0, ws + OFF_C0, 4, 0);
  kLayer<<<4, 256, 0, stream>>>(ws + OFF_P0, ws + OFF_C0, Wout, bout,
                                 ws + OFF_G, ws + OFF_S, ws + OFF_P1, ws + OFF_C1, 1, 0);
  kNorm<<<1, 256, 0, stream>>>(ws + OFF_P1, ws + OFF_C1, ws + OFF_G, ws + OFF_S,
                               ws + OFF_MO, ws + OFF_CO);
  kApply<<<1024, 256, 0, stream>>>(x, ws + OFF_MO, ws + OFF_CO, out);
}